// Round 10
// baseline (89.535 us; speedup 1.0000x reference)
//
#include <hip/hip_runtime.h>
#include <hip/hip_cooperative_groups.h>
#include <math.h>

namespace cg = cooperative_groups;

#define NN   8
#define INCH 32
#define INN  50000
#define OUTC 64
#define OUTN 8192
#define DD   32
#define CC   256            // NN*INCH
#define NPL  8              // c-planes (== #XCDs)
#define PLDW ((size_t)INN * 16)   // dwords per plane: 50000 rows x 16 dwords(64B) = 3.2 MB

__device__ __forceinline__ unsigned f2bf_u(float f) {
  unsigned u = __float_as_uint(f);
  return (u + 0x7FFFu + ((u >> 16) & 1u)) >> 16;   // round-nearest-even
}

// dword convention: yTc plane p, row j, pos q (0..15) holds bf16 pair (c_lo, c_lo+128),
// c_lo = p*16 + q.

// Kernel 1 (unchanged, proven): x*nf -> yTc (bf16 pairs).
__global__ __launch_bounds__(256) void prep_kernel(
    const float* __restrict__ x, const float* __restrict__ nf, unsigned* __restrict__ yTc) {
  __shared__ float tile[CC][33];   // stride 33 words: <=2-way banks all phases
  const int t = threadIdx.x;
  const int j0 = blockIdx.x * 32;
  const int jmax = min(32, INN - j0);   // 50000 = 1562*32 + 16

  const int q  = t & 7;
  const int r0 = t >> 3;

  if (q * 4 < jmax) {
    const float4 nv = *(const float4*)(nf + (size_t)r0 * INN + j0 + 4 * q);  // loop-invariant
    #pragma unroll
    for (int p = 0; p < 8; ++p) {
      const int c = (p << 5) + r0;
      const float4 xv = *(const float4*)(x + (size_t)c * INN + j0 + 4 * q);
      float4 pr;
      pr.x = xv.x * nv.x; pr.y = xv.y * nv.y; pr.z = xv.z * nv.z; pr.w = xv.w * nv.w;
      *(float4*)&tile[c][4 * q] = pr;   // bank (r0+4q)%32 -> <=2-way
    }
  }
  __syncthreads();

  const int lane = t & 63;
  const int wave = t >> 6;
  #pragma unroll
  for (int r = 0; r < 8; ++r) {
    const int jl = wave * 8 + r;
    if (jl < jmax) {
      #pragma unroll
      for (int e = 0; e < 2; ++e) {
        const int clo = lane + 64 * e;                 // 0..127
        const unsigned lo = f2bf_u(tile[clo][jl]);     // bank (lane+jl)%32 -> 2-way (free)
        const unsigned hi = f2bf_u(tile[clo + 128][jl]);
        const int pl  = clo >> 4;
        const int pos = clo & 15;
        yTc[(size_t)pl * PLDW + (size_t)(j0 + jl) * 16 + pos] = lo | (hi << 16);
      }
    }
  }
}

// Kernel 2 (cooperative, grid=256 = 1 block/CU): phase A gather (plane b%8 pinned to
// XCD b%8), grid.sync (device-scope fence), phase B out (bias + GEMM).
__global__ __launch_bounds__(512) void go_kernel(
    const unsigned* __restrict__ yTc, const int* __restrict__ A,
    const float* __restrict__ ft, const float* __restrict__ bias,
    unsigned* __restrict__ red32, float* __restrict__ out) {
  __shared__ __align__(16) char smem[24832];   // union: Al 16.9KB | rtile 16.6KB + ftl 8KB
  const int t = threadIdx.x;
  const int b = blockIdx.x;
  cg::grid_group grid = cg::this_grid();

  // ---------------- phase A: gather + max ----------------
  {
    int* Al = (int*)smem;                      // [128][33] padded
    const int ck = b & 7;                      // plane == XCD (grid=256 round-robin)
    const int ob = b >> 3;                     // 0..31
    const unsigned* plane = yTc + (size_t)ck * PLDW;
    const int osub = t >> 2;                   // 0..127
    const int cq   = t & 3;

    #pragma unroll
    for (int pp = 0; pp < 2; ++pp) {
      const int o0 = ob * 256 + pp * 128;
      #pragma unroll
      for (int k = 0; k < 8; ++k) {
        const int f = k * 512 + t;             // 0..4095, coalesced
        Al[(f >> 5) * 33 + (f & 31)] = A[(size_t)o0 * DD + f];
      }
      __syncthreads();

      float l0 = -INFINITY, l1 = -INFINITY, l2 = -INFINITY, l3 = -INFINITY;
      float h0 = -INFINITY, h1 = -INFINITY, h2 = -INFINITY, h3 = -INFINITY;
      #pragma unroll 8
      for (int d = 0; d < 32; ++d) {
        const int idx = Al[osub * 33 + d];     // bank (osub+d)%32, 4-lane broadcast
        const uint4 v = *(const uint4*)(plane + (size_t)idx * 16 + cq * 4);  // 16x64B segs
        l0 = fmaxf(l0, __uint_as_float(v.x << 16));  h0 = fmaxf(h0, __uint_as_float(v.x & 0xffff0000u));
        l1 = fmaxf(l1, __uint_as_float(v.y << 16));  h1 = fmaxf(h1, __uint_as_float(v.y & 0xffff0000u));
        l2 = fmaxf(l2, __uint_as_float(v.z << 16));  h2 = fmaxf(h2, __uint_as_float(v.z & 0xffff0000u));
        l3 = fmaxf(l3, __uint_as_float(v.w << 16));  h3 = fmaxf(h3, __uint_as_float(v.w & 0xffff0000u));
      }
      uint4 pk;   // repack exact (values are bf16-exact)
      pk.x = (__float_as_uint(l0) >> 16) | (__float_as_uint(h0) & 0xffff0000u);
      pk.y = (__float_as_uint(l1) >> 16) | (__float_as_uint(h1) & 0xffff0000u);
      pk.z = (__float_as_uint(l2) >> 16) | (__float_as_uint(h2) & 0xffff0000u);
      pk.w = (__float_as_uint(l3) >> 16) | (__float_as_uint(h3) & 0xffff0000u);
      *(uint4*)(red32 + (size_t)(o0 + osub) * 128 + ck * 16 + cq * 4) = pk;
      __syncthreads();
    }
  }

  grid.sync();   // device-scope: red32 visible across XCDs

  // ---------------- phase B: out = red @ ft + bias ----------------
  {
    float* rtile = (float*)smem;               // [64][65]
    float* ftl   = (float*)(smem + 64 * 65 * 4); // [32][64] flat
    const int lane = t & 63;
    const int wv   = t >> 6;                   // 0..7

    #pragma unroll
    for (int rep = 0; rep < 2; ++rep) {
      const int tile = b + rep * 256;          // 0..511
      const int np = tile >> 7;                // 0..3
      const int ot = tile & 127;
      const int o0 = ot * 64;
      const int hi = np >> 1;                  // dword half select
      const int sb = (np & 1) * 64;            // dword-slot base

      #pragma unroll
      for (int q = 0; q < 4; ++q) {
        const int idx = q * 512 + t;           // 2048 floats
        ftl[idx] = ft[idx];
      }
      {
        const int r = t >> 3;                  // 0..63
        const int g = t & 7;
        const unsigned* src = red32 + (size_t)(o0 + r) * 128 + sb + g * 8;
        const uint4 v0 = *(const uint4*)(src);
        const uint4 v1 = *(const uint4*)(src + 4);
        const unsigned w[8] = {v0.x, v0.y, v0.z, v0.w, v1.x, v1.y, v1.z, v1.w};
        float* dst = &rtile[r * 65 + g * 8];   // bank (r+8g+u)%32 -> <=2-way
        #pragma unroll
        for (int u = 0; u < 8; ++u)
          dst[u] = __uint_as_float(hi ? (w[u] & 0xffff0000u) : (w[u] << 16));
      }
      __syncthreads();

      const int n  = np * 2 + (wv & 1);
      const int kh = (wv >> 1) * 16;
      const int cb = (wv & 1) * 32;

      float rv[32];
      #pragma unroll
      for (int i = 0; i < 32; ++i) rv[i] = rtile[lane * 65 + cb + i];   // 2-way (free)

      float acc[16];
      #pragma unroll
      for (int kk = 0; kk < 16; ++kk) acc[kk] = 0.f;
      #pragma unroll
      for (int i = 0; i < 32; ++i) {
        #pragma unroll
        for (int kk = 0; kk < 16; ++kk)
          acc[kk] += rv[i] * ftl[i * 64 + kh + kk];   // uniform addr -> broadcast
      }

      float* op = out + (size_t)n * OUTC * OUTN + o0 + lane;
      const float* bp = bias + o0 + lane;
      #pragma unroll
      for (int kk = 0; kk < 16; ++kk) {
        const int k = kh + kk;
        op[(size_t)k * OUTN] = acc[kk] + bp[(size_t)k * OUTN];   // 256B-contiguous stores
      }
      __syncthreads();
    }
  }
}

extern "C" void kernel_launch(void* const* d_in, const int* in_sizes, int n_in,
                              void* d_out, int out_size, void* d_ws, size_t ws_size,
                              hipStream_t stream) {
  const float* x    = (const float*)d_in[0];
  const float* nf   = (const float*)d_in[1];
  const float* ft   = (const float*)d_in[2];
  const float* bias = (const float*)d_in[3];
  const int*   A    = (const int*)d_in[4];
  float* out = (float*)d_out;

  unsigned* yTc   = (unsigned*)d_ws;                           // 8 x 3.2 MB = 25.6 MB
  unsigned* red32 = (unsigned*)((char*)d_ws + NPL * PLDW * 4); // 8192*128*4 = 4.2 MB

  hipLaunchKernelGGL(prep_kernel, dim3((INN + 31) / 32), dim3(256), 0, stream, x, nf, yTc);

  void* args[6];
  const unsigned* yTc_a = yTc;  const int* A_a = A;  const float* ft_a = ft;
  const float* bias_a = bias;   unsigned* red_a = red32;  float* out_a = out;
  args[0] = (void*)&yTc_a;  args[1] = (void*)&A_a;   args[2] = (void*)&ft_a;
  args[3] = (void*)&bias_a; args[4] = (void*)&red_a; args[5] = (void*)&out_a;
  hipLaunchCooperativeKernel((void*)go_kernel, dim3(256), dim3(512), args, 0, stream);
}

// Round 11
// 47.647 us; speedup vs baseline: 1.8792x; 1.8792x over previous
//
#include <hip/hip_runtime.h>
#include <math.h>

#define NN   8
#define INCH 32
#define INN  50000
#define OUTC 64
#define OUTN 8192
#define DD   32
#define CC   256            // NN*INCH
#define NPL  8              // c-planes
#define PLDW ((size_t)INN * 16)   // dwords per plane: 50000 rows x 16 dwords(64B) = 3.2 MB

__device__ __forceinline__ unsigned f2bf_u(float f) {
  unsigned u = __float_as_uint(f);
  return (u + 0x7FFFu + ((u >> 16) & 1u)) >> 16;   // round-nearest-even
}

// dword convention: yTc plane p, row j, pos q (0..15) holds bf16 pair (c_lo, c_lo+128),
// c_lo = p*16 + q.

// Kernel 1 (proven): x*nf -> yTc (bf16 pairs). Global reads: 8 lanes/row -> 128B segments.
__global__ __launch_bounds__(256) void prep_kernel(
    const float* __restrict__ x, const float* __restrict__ nf, unsigned* __restrict__ yTc) {
  __shared__ float tile[CC][33];   // stride 33 words: <=2-way banks all phases
  const int t = threadIdx.x;
  const int j0 = blockIdx.x * 32;
  const int jmax = min(32, INN - j0);   // 50000 = 1562*32 + 16

  const int q  = t & 7;
  const int r0 = t >> 3;

  if (q * 4 < jmax) {
    const float4 nv = *(const float4*)(nf + (size_t)r0 * INN + j0 + 4 * q);  // loop-invariant
    #pragma unroll
    for (int p = 0; p < 8; ++p) {
      const int c = (p << 5) + r0;
      const float4 xv = *(const float4*)(x + (size_t)c * INN + j0 + 4 * q);
      float4 pr;
      pr.x = xv.x * nv.x; pr.y = xv.y * nv.y; pr.z = xv.z * nv.z; pr.w = xv.w * nv.w;
      *(float4*)&tile[c][4 * q] = pr;   // bank (r0+4q)%32 -> <=2-way
    }
  }
  __syncthreads();

  const int lane = t & 63;
  const int wave = t >> 6;
  #pragma unroll
  for (int r = 0; r < 8; ++r) {
    const int jl = wave * 8 + r;
    if (jl < jmax) {
      #pragma unroll
      for (int e = 0; e < 2; ++e) {
        const int clo = lane + 64 * e;                 // 0..127
        const unsigned lo = f2bf_u(tile[clo][jl]);     // bank (lane+jl)%32 -> 2-way (free)
        const unsigned hi = f2bf_u(tile[clo + 128][jl]);
        const int pl  = clo >> 4;
        const int pos = clo & 15;
        yTc[(size_t)pl * PLDW + (size_t)(j0 + jl) * 16 + pos] = lo | (hi << 16);
      }
    }
  }
}

// Kernel 2: c-sliced gather, occupancy-doubled. 2048 blocks (plane=b%8, 32 o's each),
// 256 thr, 8 blocks/CU = 32 waves/CU. Thread (osub,cq,dh): d = 2k+dh, 16 iters,
// uint4 loads (16x64B segs per wave-instr), then shfl_xor(1) merge, uint2 store.
__global__ __launch_bounds__(256, 8) void gather_kernel(
    const unsigned* __restrict__ yTc, const int* __restrict__ A, unsigned* __restrict__ red32) {
  __shared__ int Al[32 * 33];   // A[o0..o0+31][0..31], padded
  const int t = threadIdx.x;
  const int ck = blockIdx.x & 7;
  const int ob = blockIdx.x >> 3;   // 0..255
  const int o0 = ob * 32;

  #pragma unroll
  for (int k = 0; k < 4; ++k) {
    const int f = k * 256 + t;                      // 0..1023, coalesced
    Al[(f >> 5) * 33 + (f & 31)] = A[(size_t)o0 * DD + f];
  }
  __syncthreads();

  const unsigned* plane = yTc + (size_t)ck * PLDW;
  const int osub = t >> 3;          // 0..31
  const int cq   = (t >> 1) & 3;    // 0..3
  const int dh   = t & 1;           // 0..1

  float l0 = -INFINITY, l1 = -INFINITY, l2 = -INFINITY, l3 = -INFINITY;
  float h0 = -INFINITY, h1 = -INFINITY, h2 = -INFINITY, h3 = -INFINITY;

  #pragma unroll 8
  for (int k = 0; k < 16; ++k) {
    const int d = 2 * k + dh;
    const int idx = Al[osub * 33 + d];   // <=16 distinct addrs/wave, conflict-free broadcast
    const uint4 v = *(const uint4*)(plane + (size_t)idx * 16 + cq * 4);  // 16x64B segs/instr
    l0 = fmaxf(l0, __uint_as_float(v.x << 16));  h0 = fmaxf(h0, __uint_as_float(v.x & 0xffff0000u));
    l1 = fmaxf(l1, __uint_as_float(v.y << 16));  h1 = fmaxf(h1, __uint_as_float(v.y & 0xffff0000u));
    l2 = fmaxf(l2, __uint_as_float(v.z << 16));  h2 = fmaxf(h2, __uint_as_float(v.z & 0xffff0000u));
    l3 = fmaxf(l3, __uint_as_float(v.w << 16));  h3 = fmaxf(h3, __uint_as_float(v.w & 0xffff0000u));
  }
  // merge lane pairs (t, t^1): full 32-d max lands in both lanes
  l0 = fmaxf(l0, __shfl_xor(l0, 1));  h0 = fmaxf(h0, __shfl_xor(h0, 1));
  l1 = fmaxf(l1, __shfl_xor(l1, 1));  h1 = fmaxf(h1, __shfl_xor(h1, 1));
  l2 = fmaxf(l2, __shfl_xor(l2, 1));  h2 = fmaxf(h2, __shfl_xor(h2, 1));
  l3 = fmaxf(l3, __shfl_xor(l3, 1));  h3 = fmaxf(h3, __shfl_xor(h3, 1));

  // repack exact; each lane stores its uint2 half: dh=0 -> dwords {0,1}, dh=1 -> {2,3}
  uint2 pk;
  if (dh == 0) {
    pk.x = (__float_as_uint(l0) >> 16) | (__float_as_uint(h0) & 0xffff0000u);
    pk.y = (__float_as_uint(l1) >> 16) | (__float_as_uint(h1) & 0xffff0000u);
  } else {
    pk.x = (__float_as_uint(l2) >> 16) | (__float_as_uint(h2) & 0xffff0000u);
    pk.y = (__float_as_uint(l3) >> 16) | (__float_as_uint(h3) & 0xffff0000u);
  }
  // red32[o][s]: 64B contiguous per o across 8 lanes -> coalesced
  *(uint2*)(red32 + (size_t)(o0 + osub) * 128 + ck * 16 + cq * 4 + dh * 2) = pk;
}

// Kernel 3 (proven): out[n,k,o] = sum_i red[o][n*32+i]*ft[i][k] + bias[k][o]
__global__ __launch_bounds__(256) void out_kernel(
    const unsigned* __restrict__ red32, const float* __restrict__ ft,
    const float* __restrict__ bias, float* __restrict__ out) {
  __shared__ float rtile[64][65];   // pad 65 -> <=2-way
  __shared__ float ftl[32][64];
  const int t = threadIdx.x;
  const int lane = t & 63;
  const int wave = t >> 6;
  const int np = blockIdx.x >> 7;   // 0..3, c0 = np*64
  const int ot = blockIdx.x & 127;  // 0..127
  const int o0 = ot * 64;
  const int hi = np >> 1;           // 0: lo16 (c<128), 1: hi16 (c>=128)
  const int sb = (np & 1) * 64;     // dword-slot base

  #pragma unroll
  for (int q = 0; q < 8; ++q) {
    const int idx = q * 256 + t;
    ftl[idx >> 6][idx & 63] = ft[idx];
  }
  #pragma unroll
  for (int i = 0; i < 2; ++i) {
    const int r = (t >> 3) + 32 * i;
    const int g = t & 7;
    const unsigned* src = red32 + (size_t)(o0 + r) * 128 + sb + g * 8;
    const uint4 v0 = *(const uint4*)(src);
    const uint4 v1 = *(const uint4*)(src + 4);
    const unsigned w[8] = {v0.x, v0.y, v0.z, v0.w, v1.x, v1.y, v1.z, v1.w};
    float* dst = &rtile[r][g * 8];   // bank (r+8g+u)%32 -> 2-way (free)
    #pragma unroll
    for (int u = 0; u < 8; ++u)
      dst[u] = __uint_as_float(hi ? (w[u] & 0xffff0000u) : (w[u] << 16));
  }
  __syncthreads();

  const int n  = np * 2 + (wave & 1);
  const int kh = (wave >> 1) * 32;
  const int cb = (wave & 1) * 32;

  float rv[32];
  #pragma unroll
  for (int i = 0; i < 32; ++i) rv[i] = rtile[lane][cb + i];   // 2-way

  float acc[32];
  #pragma unroll
  for (int kk = 0; kk < 32; ++kk) acc[kk] = 0.f;
  #pragma unroll
  for (int i = 0; i < 32; ++i) {
    #pragma unroll
    for (int kk = 0; kk < 32; ++kk)
      acc[kk] += rv[i] * ftl[i][kh + kk];   // uniform addr -> broadcast
  }

  float* op = out + (size_t)n * OUTC * OUTN + o0 + lane;
  const float* bp = bias + o0 + lane;
  #pragma unroll
  for (int kk = 0; kk < 32; ++kk) {
    const int k = kh + kk;
    op[(size_t)k * OUTN] = acc[kk] + bp[(size_t)k * OUTN];   // 256B-contiguous stores
  }
}

extern "C" void kernel_launch(void* const* d_in, const int* in_sizes, int n_in,
                              void* d_out, int out_size, void* d_ws, size_t ws_size,
                              hipStream_t stream) {
  const float* x    = (const float*)d_in[0];
  const float* nf   = (const float*)d_in[1];
  const float* ft   = (const float*)d_in[2];
  const float* bias = (const float*)d_in[3];
  const int*   A    = (const int*)d_in[4];
  float* out = (float*)d_out;

  unsigned* yTc   = (unsigned*)d_ws;                           // 8 x 3.2 MB = 25.6 MB
  unsigned* red32 = (unsigned*)((char*)d_ws + NPL * PLDW * 4); // 8192*128*4 = 4.2 MB

  hipLaunchKernelGGL(prep_kernel,   dim3((INN + 31) / 32),   dim3(256), 0, stream, x, nf, yTc);
  hipLaunchKernelGGL(gather_kernel, dim3((OUTN / 32) * NPL), dim3(256), 0, stream, yTc, A, red32);
  hipLaunchKernelGGL(out_kernel,    dim3(512),               dim3(256), 0, stream, red32, ft, bias, out);
}